// Round 18
// baseline (334.216 us; speedup 1.0000x reference)
//
#include <hip/hip_runtime.h>
#include <hip/hip_bf16.h>
#include <math.h>

#define N_NODES 50000
#define E_EDGES 800000
#define NFEAT 16
#define EFEAT 8
#define HID 32
#define HEADS 4
#define HC 128
#define SCAN_NB ((N_NODES + 255) / 256)   // 196

typedef float f4v __attribute__((ext_vector_type(4)));

__device__ __forceinline__ float lrelu(float v) { return v > 0.f ? v : 0.2f * v; }
__device__ __forceinline__ float bflo(unsigned u) { return __uint_as_float(u << 16); }
__device__ __forceinline__ float bfhi(unsigned u) { return __uint_as_float(u & 0xffff0000u); }
__device__ __forceinline__ float bf2f(__hip_bfloat16 v) {
    return __uint_as_float(((unsigned)__hip_bfloat16_raw(v).x) << 16);
}
__device__ __forceinline__ f4v relu4(f4v v) {
    f4v r;
    r.x = v.x > 0.f ? v.x : 0.f;
    r.y = v.y > 0.f ? v.y : 0.f;
    r.z = v.z > 0.f ? v.z : 0.f;
    r.w = v.w > 0.f ? v.w : 0.f;
    return r;
}

// ---- K1: h = x @ W ; alpha_src/dst = einsum(h, aS/aD) per head ----
// SCALARX (HOUT>=64): x rows via wave-uniform scalar path (s_load).
// XBF16: x rows stored bf16 -> half the scalar-load bytes (layer 2).
template<int FIN, int HOUT, int H, bool BF16OUT, int NPT, bool XBF16>
__global__ void k1_gemm_alpha(const void* __restrict__ xin, const float* __restrict__ W,
                              const float* __restrict__ aS, const float* __restrict__ aD,
                              void* __restrict__ hout, float* __restrict__ asrc,
                              float* __restrict__ adst, int n_nodes)
{
    constexpr int GROUPS = 256 / HOUT;
    constexpr int NPB = GROUPS * NPT;
    constexpr bool SCALARX = (HOUT >= 64);
    const float* xf = (const float*)xin;
    const __hip_bfloat16* xb = (const __hip_bfloat16*)xin;
    __shared__ float xs[SCALARX ? 1 : NPB * (FIN + 1)];
    const int tid = threadIdx.x;
    const int nb0 = blockIdx.x * NPB;
    const int c = tid % HOUT;
    const int g = tid / HOUT;

    if constexpr (!SCALARX) {
        for (int idx = tid; idx < NPB * FIN; idx += 256) {
            int node = idx / FIN, k = idx % FIN;
            int gn = nb0 + node;
            xs[node * (FIN + 1) + k] = (gn < n_nodes) ? xf[(size_t)gn * FIN + k] : 0.f;
        }
        __syncthreads();
    }

    const int head = c / HID;
    const int cc = c % HID;
    const float aSv = aS[head * HID + cc];
    const float aDv = aD[head * HID + cc];
    float acc[NPT];
#pragma unroll
    for (int i = 0; i < NPT; i++) acc[i] = 0.f;

    if constexpr (SCALARX) {
        if constexpr (XBF16) {
            const __hip_bfloat16* xr[NPT];
#pragma unroll
            for (int i = 0; i < NPT; i++) {
                int n = nb0 + g * NPT + i;
                unsigned nu = (unsigned)__builtin_amdgcn_readfirstlane(n < n_nodes ? n : 0);
                xr[i] = xb + (size_t)nu * FIN;
            }
#pragma unroll 8
            for (int k = 0; k < FIN; k++) {
                float w = W[k * HOUT + c];
#pragma unroll
                for (int i = 0; i < NPT; i++) acc[i] += w * bf2f(xr[i][k]);
            }
        } else {
            const float* xr[NPT];
#pragma unroll
            for (int i = 0; i < NPT; i++) {
                int n = nb0 + g * NPT + i;
                unsigned nu = (unsigned)__builtin_amdgcn_readfirstlane(n < n_nodes ? n : 0);
                xr[i] = xf + (size_t)nu * FIN;
            }
#pragma unroll 8
            for (int k = 0; k < FIN; k++) {
                float w = W[k * HOUT + c];
#pragma unroll
                for (int i = 0; i < NPT; i++) acc[i] += w * xr[i][k];
            }
        }
    } else {
        for (int k = 0; k < FIN; k++) {
            float w = W[k * HOUT + c];
#pragma unroll
            for (int i = 0; i < NPT; i++)
                acc[i] += w * xs[(g * NPT + i) * (FIN + 1) + k];
        }
    }

#pragma unroll
    for (int i = 0; i < NPT; i++) {
        int n = nb0 + g * NPT + i;
        bool ok = (n < n_nodes);
        float h = acc[i];
        if (ok) {
            if (BF16OUT)
                ((__hip_bfloat16*)hout)[(size_t)n * HOUT + c] = __float2bfloat16(h);
            else
                ((float*)hout)[(size_t)n * HOUT + c] = h;
        }
        float pa = h * aSv, pb = h * aDv;
#pragma unroll
        for (int off = 16; off >= 1; off >>= 1) {
            pa += __shfl_xor(pa, off, 32);
            pb += __shfl_xor(pb, off, 32);
        }
        if (ok && cc == 0) { asrc[n * H + head] = pa; adst[n * H + head] = pb; }
    }
}

// ---- CSR build: histogram(+rank) -> 3-phase scan -> atomic-free scatter ----
__global__ void kc_count(const int* __restrict__ ei1, int* __restrict__ cnt,
                         int* __restrict__ rank)
{
    int e = blockIdx.x * 256 + threadIdx.x;
    if (e >= E_EDGES) return;
    rank[e] = atomicAdd(&cnt[ei1[e]], 1);
}

__global__ __launch_bounds__(256) void kc_blocksum(const int* __restrict__ cnt,
                                                   int* __restrict__ bsum)
{
    __shared__ int sd[256];
    const int tid = threadIdx.x;
    int i = blockIdx.x * 256 + tid;
    int v = (i < N_NODES) ? cnt[i] : 0;
    sd[tid] = v;
    __syncthreads();
    for (int off = 128; off >= 1; off >>= 1) {
        if (tid < off) sd[tid] += sd[tid + off];
        __syncthreads();
    }
    if (tid == 0) bsum[blockIdx.x] = sd[0];
}

__global__ __launch_bounds__(256) void kc_scanbsum(const int* __restrict__ bsum,
                                                   int* __restrict__ bofs)
{
    __shared__ int sd[256];
    const int tid = threadIdx.x;
    int v = (tid < SCAN_NB) ? bsum[tid] : 0;
    sd[tid] = v;
    __syncthreads();
    for (int off = 1; off < 256; off <<= 1) {
        int u = (tid >= off) ? sd[tid - off] : 0;
        __syncthreads();
        sd[tid] += u;
        __syncthreads();
    }
    if (tid < SCAN_NB) bofs[tid] = sd[tid] - v;
}

__global__ __launch_bounds__(256) void kc_apply(const int* __restrict__ cnt,
                                                const int* __restrict__ bofs,
                                                int* __restrict__ rowptr)
{
    __shared__ int sd[256];
    const int tid = threadIdx.x;
    int i = blockIdx.x * 256 + tid;
    int v = (i < N_NODES) ? cnt[i] : 0;
    sd[tid] = v;
    __syncthreads();
    for (int off = 1; off < 256; off <<= 1) {
        int u = (tid >= off) ? sd[tid - off] : 0;
        __syncthreads();
        sd[tid] += u;
        __syncthreads();
    }
    int excl = sd[tid] - v + bofs[blockIdx.x];
    if (i < N_NODES) rowptr[i] = excl;
}

__global__ void kc_scatter(const int* __restrict__ ei0, const int* __restrict__ ei1,
                           const int* __restrict__ rowptr, const int* __restrict__ rank,
                           int* __restrict__ srcs)
{
    int e = blockIdx.x * 256 + threadIdx.x;
    if (e >= E_EDGES) return;
    srcs[rowptr[ei1[e]] + rank[e]] = ei0[e];
}

// ---- fused aggregation: segment-softmax with FIXED reference point ----
// OBF16: write the (ELU'd) output as bf16 (feeds layer-2's bf16 x path).
template<int H, int C, bool DO_ELU, bool BF16H, bool OBF16>
__global__ __launch_bounds__(256) void k_aggr(
    const float* __restrict__ asrc, const float* __restrict__ adst,
    const void* __restrict__ hbuf, const int* __restrict__ rowptr,
    const int* __restrict__ deg, const int* __restrict__ srcs,
    const float* __restrict__ b, void* __restrict__ outp)
{
    constexpr int HCL = H * C;
    constexpr int TPE = HCL / 2;
    constexpr int NPB = 256 / TPE;
    constexpr bool UNI = (TPE == 64);
    const int t = threadIdx.x % TPE;
    const int n = blockIdx.x * NPB + threadIdx.x / TPE;
    if (n >= N_NODES) return;
    const int c0 = 2 * t;
    const int head = c0 / C;
    const float adstv = adst[n * H + head];
    const unsigned* hbu = (const unsigned*)hbuf;
    const float* hbf = (const float*)hbuf;
    const float m0 = lrelu(asrc[n * H + head] + adstv);   // fixed reference
    float ssum = 1.f;   // self-loop: exp(m0 - m0) = 1
    float a0, a1;
    if (BF16H) {
        unsigned u = hbu[(size_t)n * TPE + t];
        a0 = bflo(u); a1 = bfhi(u);
    } else {
        float2 hv = *(const float2*)(hbf + (size_t)n * HCL + c0);
        a0 = hv.x; a1 = hv.y;
    }
    const int base = rowptr[n];
    const int dg = deg[n];
    int i = 0;

    if constexpr (UNI && BF16H) {
        for (; i + 8 <= dg; i += 8) {
            int s[8];
#pragma unroll
            for (int u = 0; u < 8; u++)
                s[u] = __builtin_amdgcn_readfirstlane(srcs[base + i + u]);
            float ex[8];
#pragma unroll
            for (int u = 0; u < 8; u++)
                ex[u] = __expf(lrelu(asrc[s[u] * H + head] + adstv) - m0);
            unsigned hu[8];
#pragma unroll
            for (int u = 0; u < 8; u++)
                hu[u] = hbu[(size_t)s[u] * TPE + t];
#pragma unroll
            for (int u = 0; u < 8; u++) {
                ssum += ex[u];
                a0 += ex[u] * bflo(hu[u]);
                a1 += ex[u] * bfhi(hu[u]);
            }
        }
    }

    for (; i + 4 <= dg; i += 4) {
        int s0 = srcs[base + i + 0];
        int s1 = srcs[base + i + 1];
        int s2 = srcs[base + i + 2];
        int s3 = srcs[base + i + 3];
        if (UNI) {
            s0 = __builtin_amdgcn_readfirstlane(s0);
            s1 = __builtin_amdgcn_readfirstlane(s1);
            s2 = __builtin_amdgcn_readfirstlane(s2);
            s3 = __builtin_amdgcn_readfirstlane(s3);
        }
        float ex[4];
        ex[0] = __expf(lrelu(asrc[s0 * H + head] + adstv) - m0);
        ex[1] = __expf(lrelu(asrc[s1 * H + head] + adstv) - m0);
        ex[2] = __expf(lrelu(asrc[s2 * H + head] + adstv) - m0);
        ex[3] = __expf(lrelu(asrc[s3 * H + head] + adstv) - m0);
        float hx[4], hy[4];
        if (BF16H) {
            unsigned u0 = hbu[(size_t)s0 * TPE + t];
            unsigned u1 = hbu[(size_t)s1 * TPE + t];
            unsigned u2 = hbu[(size_t)s2 * TPE + t];
            unsigned u3 = hbu[(size_t)s3 * TPE + t];
            hx[0] = bflo(u0); hy[0] = bfhi(u0);
            hx[1] = bflo(u1); hy[1] = bfhi(u1);
            hx[2] = bflo(u2); hy[2] = bfhi(u2);
            hx[3] = bflo(u3); hy[3] = bfhi(u3);
        } else {
            float2 h0 = *(const float2*)(hbf + (size_t)s0 * HCL + c0);
            float2 h1 = *(const float2*)(hbf + (size_t)s1 * HCL + c0);
            float2 h2 = *(const float2*)(hbf + (size_t)s2 * HCL + c0);
            float2 h3 = *(const float2*)(hbf + (size_t)s3 * HCL + c0);
            hx[0] = h0.x; hy[0] = h0.y;
            hx[1] = h1.x; hy[1] = h1.y;
            hx[2] = h2.x; hy[2] = h2.y;
            hx[3] = h3.x; hy[3] = h3.y;
        }
#pragma unroll
        for (int u = 0; u < 4; u++) {
            ssum += ex[u];
            a0 += ex[u] * hx[u];
            a1 += ex[u] * hy[u];
        }
    }
    for (; i < dg; i++) {
        int s = srcs[base + i];
        if (UNI) s = __builtin_amdgcn_readfirstlane(s);
        float ex = __expf(lrelu(asrc[s * H + head] + adstv) - m0);
        float hxv, hyv;
        if (BF16H) {
            unsigned u = hbu[(size_t)s * TPE + t];
            hxv = bflo(u); hyv = bfhi(u);
        } else {
            float2 hs = *(const float2*)(hbf + (size_t)s * HCL + c0);
            hxv = hs.x; hyv = hs.y;
        }
        ssum += ex;
        a0 += ex * hxv;
        a1 += ex * hyv;
    }
    float inv = 1.f / (ssum + 1e-16f);
    float v0 = a0 * inv + b[c0];
    float v1 = a1 * inv + b[c0 + 1];
    if (DO_ELU) {
        v0 = v0 > 0.f ? v0 : __expf(v0) - 1.f;
        v1 = v1 > 0.f ? v1 : __expf(v1) - 1.f;
    }
    if constexpr (OBF16) {
        __hip_bfloat16* ob = (__hip_bfloat16*)outp;
        ob[(size_t)n * HCL + c0]     = __float2bfloat16(v0);
        ob[(size_t)n * HCL + c0 + 1] = __float2bfloat16(v1);
    } else {
        *(float2*)((float*)outp + (size_t)n * HCL + c0) = make_float2(v0, v1);
    }
}

// ---- K5a: node-level precompute for MLP layer 1 (bf16 output, unchanged) ----
__global__ __launch_bounds__(256) void k5a_precomp(
    const float* __restrict__ h3, const float* __restrict__ Wm1,
    __hip_bfloat16* __restrict__ Pb)
{
    __shared__ __align__(16) float w[64 * 32];
    __shared__ __align__(16) float hsh[16][33];
    const int tid = threadIdx.x;
    for (int i = tid; i < 64 * 32; i += 256) w[i] = Wm1[i];
    const int nb0 = blockIdx.x * 16;
    for (int idx = tid; idx < 16 * 32; idx += 256) {
        int node = idx / 32, k = idx % 32;
        int gn = nb0 + node;
        hsh[node][k] = (gn < N_NODES) ? h3[gn * 32 + k] : 0.f;
    }
    __syncthreads();
    const int c = tid % 64;
    const int part = c / 32;
    const int j = c % 32;
    for (int ln = tid / 64; ln < 16; ln += 4) {
        int gn = nb0 + ln;
        if (gn >= N_NODES) break;
        float sum = 0.f;
#pragma unroll
        for (int k = 0; k < 32; k++)
            sum += hsh[ln][k] * w[(part * 32 + k) * 32 + j];
        Pb[(size_t)gn * 64 + c] = __float2bfloat16(sum);
    }
}

// ---- K5b: per-edge MLP; scalar weights + packed f4v FMAs (unchanged) ----
__global__ __launch_bounds__(256, 4) void k5b_mlp(
                       const int* __restrict__ ei0, const int* __restrict__ ei1,
                       const __hip_bfloat16* __restrict__ Pb, const float* __restrict__ ea,
                       const float* __restrict__ Wm1, const float* __restrict__ bm1,
                       const float* __restrict__ Wm2, const float* __restrict__ bm2,
                       const float* __restrict__ Wm3, const float* __restrict__ bm3,
                       float* __restrict__ out)
{
    const int e = blockIdx.x * 256 + threadIdx.x;
    if (e >= E_EDGES) return;
    const int s = ei0[e], d = ei1[e];

    const f4v* bm1v = (const f4v*)bm1;
    f4v z1v[8];
#pragma unroll
    for (int q = 0; q < 8; q++) z1v[q] = bm1v[q];

    const f4v* eav = (const f4v*)(ea + (size_t)e * 8);
#pragma unroll
    for (int kq = 0; kq < 2; kq++) {
        f4v v = eav[kq];
#pragma unroll
        for (int r = 0; r < 4; r++) {
            float vr = (r == 0) ? v.x : (r == 1) ? v.y : (r == 2) ? v.z : v.w;
            const f4v* w4 = (const f4v*)(Wm1 + (64 + kq * 4 + r) * 32);
#pragma unroll
            for (int q = 0; q < 8; q++) z1v[q] += w4[q] * vr;
        }
    }
    const uint4* ps4 = (const uint4*)(Pb + (size_t)s * 64);
    const uint4* pd4 = (const uint4*)(Pb + (size_t)d * 64 + 32);
#pragma unroll
    for (int q = 0; q < 4; q++) {
        uint4 a = ps4[q];
        uint4 b = pd4[q];
        f4v pa0 = {bflo(a.x), bfhi(a.x), bflo(a.y), bfhi(a.y)};
        f4v pa1 = {bflo(a.z), bfhi(a.z), bflo(a.w), bfhi(a.w)};
        f4v pb0 = {bflo(b.x), bfhi(b.x), bflo(b.y), bfhi(b.y)};
        f4v pb1 = {bflo(b.z), bfhi(b.z), bflo(b.w), bfhi(b.w)};
        z1v[2 * q + 0] += pa0 + pb0;
        z1v[2 * q + 1] += pa1 + pb1;
    }
#pragma unroll
    for (int q = 0; q < 8; q++) z1v[q] = relu4(z1v[q]);

    const f4v* bm2v = (const f4v*)bm2;
    f4v acc2v[8];
#pragma unroll
    for (int q = 0; q < 8; q++) acc2v[q] = bm2v[q];
#pragma unroll
    for (int k = 0; k < 32; k++) {
        float zk = z1v[k >> 2][k & 3];
        const f4v* w4 = (const f4v*)(Wm2 + k * 32);
#pragma unroll
        for (int q = 0; q < 8; q++) acc2v[q] += w4[q] * zk;
    }
    float z3 = bm3[0];
#pragma unroll
    for (int q = 0; q < 8; q++) {
        const float* w3q = Wm3 + 4 * q;
        float c0 = acc2v[q].x, c1 = acc2v[q].y, c2 = acc2v[q].z, c3 = acc2v[q].w;
        z3 += (c0 > 0.f ? c0 : 0.f) * w3q[0];
        z3 += (c1 > 0.f ? c1 : 0.f) * w3q[1];
        z3 += (c2 > 0.f ? c2 : 0.f) * w3q[2];
        z3 += (c3 > 0.f ? c3 : 0.f) * w3q[3];
    }

    float r = (z3 > 20.f) ? z3 : log1pf(__expf(z3));
    __builtin_nontemporal_store(r, &out[e]);
}

extern "C" void kernel_launch(void* const* d_in, const int* in_sizes, int n_in,
                              void* d_out, int out_size, void* d_ws, size_t ws_size,
                              hipStream_t stream)
{
    const float* x   = (const float*)d_in[0];
    const int*   ei  = (const int*)d_in[1];
    const int*   ei0 = ei;
    const int*   ei1 = ei + E_EDGES;
    const float* ea  = (const float*)d_in[2];
    const float* W1  = (const float*)d_in[3];
    const float* aS1 = (const float*)d_in[4];
    const float* aD1 = (const float*)d_in[5];
    const float* b1  = (const float*)d_in[6];
    const float* W2  = (const float*)d_in[7];
    const float* aS2 = (const float*)d_in[8];
    const float* aD2 = (const float*)d_in[9];
    const float* b2  = (const float*)d_in[10];
    const float* W3  = (const float*)d_in[11];
    const float* aS3 = (const float*)d_in[12];
    const float* aD3 = (const float*)d_in[13];
    const float* b3  = (const float*)d_in[14];
    const float* Wm1 = (const float*)d_in[15];
    const float* bm1 = (const float*)d_in[16];
    const float* Wm2 = (const float*)d_in[17];
    const float* bm2 = (const float*)d_in[18];
    const float* Wm3 = (const float*)d_in[19];
    const float* bm3 = (const float*)d_in[20];

    float* ws = (float*)d_ws;
    float* bufA = ws;                                    // h (bf16 L1/L2, f32 L3) / later Pb
    float* bufB = bufA + (size_t)N_NODES * HC;           // [N,128] layer output
    float* asrc = bufB + (size_t)N_NODES * HC;           // [N,4]
    float* adst = asrc + (size_t)N_NODES * HEADS;        // [N,4]
    int* cnt    = (int*)(adst + (size_t)N_NODES * HEADS);// [N]
    int* rowptr = cnt + N_NODES;                         // [N]
    int* rank   = rowptr + N_NODES;                      // [E]
    int* srcs   = rank + E_EDGES;                        // [E]
    int* bsum   = srcs + E_EDGES;                        // [SCAN_NB]
    int* bofs   = bsum + 256;                            // [SCAN_NB]

    float* out = (float*)d_out;

    // ---------------- CSR build (once; shared by all 3 layers) ----------------
    hipMemsetAsync(cnt, 0, (size_t)N_NODES * sizeof(int), stream);
    kc_count<<<(E_EDGES + 255) / 256, 256, 0, stream>>>(ei1, cnt, rank);
    kc_blocksum<<<SCAN_NB, 256, 0, stream>>>(cnt, bsum);
    kc_scanbsum<<<1, 256, 0, stream>>>(bsum, bofs);
    kc_apply<<<SCAN_NB, 256, 0, stream>>>(cnt, bofs, rowptr);
    kc_scatter<<<(E_EDGES + 255) / 256, 256, 0, stream>>>(ei0, ei1, rowptr, rank, srcs);

    // ---------------- Layer 1: x[N,16] -> bufB (ELU, bf16 out) ----------------
    k1_gemm_alpha<NFEAT, HC, HEADS, true, 4, false><<<(N_NODES + 7) / 8, 256, 0, stream>>>(
        x, W1, aS1, aD1, bufA, asrc, adst, N_NODES);
    k_aggr<HEADS, HID, true, true, true><<<(N_NODES + 3) / 4, 256, 0, stream>>>(
        asrc, adst, bufA, rowptr, cnt, srcs, b1, bufB);

    // ---------------- Layer 2: bufB(bf16)[N,128] -> bufB(f32) (ELU), NPT=4 ----------------
    k1_gemm_alpha<HC, HC, HEADS, true, 4, true><<<(N_NODES + 7) / 8, 256, 0, stream>>>(
        bufB, W2, aS2, aD2, bufA, asrc, adst, N_NODES);
    k_aggr<HEADS, HID, true, true, false><<<(N_NODES + 3) / 4, 256, 0, stream>>>(
        asrc, adst, bufA, rowptr, cnt, srcs, b2, bufB);

    // ---------------- Layer 3: bufB(f32)[N,128] -> bufB[N,32] (no act, H=1) ----------------
    k1_gemm_alpha<HC, HID, 1, false, 4, false><<<(N_NODES + 31) / 32, 256, 0, stream>>>(
        bufB, W3, aS3, aD3, bufA, asrc, adst, N_NODES);
    k_aggr<1, HID, false, false, false><<<(N_NODES + 15) / 16, 256, 0, stream>>>(
        asrc, adst, bufA, rowptr, cnt, srcs, b3, bufB);

    // ---------------- Edge MLP: node precompute (bf16), then per-edge ----------------
    __hip_bfloat16* Pb = (__hip_bfloat16*)bufA;   // bufA free after layer 3
    k5a_precomp<<<(N_NODES + 15) / 16, 256, 0, stream>>>(bufB, Wm1, Pb);
    k5b_mlp<<<(E_EDGES + 255) / 256, 256, 0, stream>>>(
        ei0, ei1, Pb, ea, Wm1, bm1, Wm2, bm2, Wm3, bm3, out);
}

// Round 19
// 291.345 us; speedup vs baseline: 1.1471x; 1.1471x over previous
//
#include <hip/hip_runtime.h>
#include <hip/hip_bf16.h>
#include <math.h>

#define N_NODES 50000
#define E_EDGES 800000
#define NFEAT 16
#define EFEAT 8
#define HID 32
#define HEADS 4
#define HC 128
#define SCAN_NB ((N_NODES + 255) / 256)   // 196

typedef float f4v __attribute__((ext_vector_type(4)));
typedef short short8 __attribute__((ext_vector_type(8)));

__device__ __forceinline__ float lrelu(float v) { return v > 0.f ? v : 0.2f * v; }
__device__ __forceinline__ float bflo(unsigned u) { return __uint_as_float(u << 16); }
__device__ __forceinline__ float bfhi(unsigned u) { return __uint_as_float(u & 0xffff0000u); }
__device__ __forceinline__ f4v relu4(f4v v) {
    f4v r;
    r.x = v.x > 0.f ? v.x : 0.f;
    r.y = v.y > 0.f ? v.y : 0.f;
    r.z = v.z > 0.f ? v.z : 0.f;
    r.w = v.w > 0.f ? v.w : 0.f;
    return r;
}

// ---- K1 (VALU form, layers 1 & 3): h = x @ W ; alpha via shfl-reduce ----
template<int FIN, int HOUT, int H, bool BF16OUT, int NPT>
__global__ void k1_gemm_alpha(const float* __restrict__ x, const float* __restrict__ W,
                              const float* __restrict__ aS, const float* __restrict__ aD,
                              void* __restrict__ hout, float* __restrict__ asrc,
                              float* __restrict__ adst, int n_nodes)
{
    constexpr int GROUPS = 256 / HOUT;
    constexpr int NPB = GROUPS * NPT;
    constexpr bool SCALARX = (HOUT >= 64);
    __shared__ float xs[SCALARX ? 1 : NPB * (FIN + 1)];
    const int tid = threadIdx.x;
    const int nb0 = blockIdx.x * NPB;
    const int c = tid % HOUT;
    const int g = tid / HOUT;

    if constexpr (!SCALARX) {
        for (int idx = tid; idx < NPB * FIN; idx += 256) {
            int node = idx / FIN, k = idx % FIN;
            int gn = nb0 + node;
            xs[node * (FIN + 1) + k] = (gn < n_nodes) ? x[(size_t)gn * FIN + k] : 0.f;
        }
        __syncthreads();
    }

    const int head = c / HID;
    const int cc = c % HID;
    const float aSv = aS[head * HID + cc];
    const float aDv = aD[head * HID + cc];
    float acc[NPT];
#pragma unroll
    for (int i = 0; i < NPT; i++) acc[i] = 0.f;

    if constexpr (SCALARX) {
        const float* xr[NPT];
#pragma unroll
        for (int i = 0; i < NPT; i++) {
            int n = nb0 + g * NPT + i;
            unsigned nu = (unsigned)__builtin_amdgcn_readfirstlane(n < n_nodes ? n : 0);
            xr[i] = x + (size_t)nu * FIN;
        }
#pragma unroll 8
        for (int k = 0; k < FIN; k++) {
            float w = W[k * HOUT + c];
#pragma unroll
            for (int i = 0; i < NPT; i++) acc[i] += w * xr[i][k];
        }
    } else {
        for (int k = 0; k < FIN; k++) {
            float w = W[k * HOUT + c];
#pragma unroll
            for (int i = 0; i < NPT; i++)
                acc[i] += w * xs[(g * NPT + i) * (FIN + 1) + k];
        }
    }

#pragma unroll
    for (int i = 0; i < NPT; i++) {
        int n = nb0 + g * NPT + i;
        bool ok = (n < n_nodes);
        float h = acc[i];
        if (ok) {
            if (BF16OUT)
                ((__hip_bfloat16*)hout)[(size_t)n * HOUT + c] = __float2bfloat16(h);
            else
                ((float*)hout)[(size_t)n * HOUT + c] = h;
        }
        float pa = h * aSv, pb = h * aDv;
#pragma unroll
        for (int off = 16; off >= 1; off >>= 1) {
            pa += __shfl_xor(pa, off, 32);
            pb += __shfl_xor(pb, off, 32);
        }
        if (ok && cc == 0) { asrc[n * H + head] = pa; adst[n * H + head] = pb; }
    }
}

// ---- W2 -> bf16 transposed [c][k] for MFMA B-fragments ----
__global__ __launch_bounds__(256) void kw_conv(const float* __restrict__ W2,
                                               short* __restrict__ W2T)
{
    int idx = blockIdx.x * 256 + threadIdx.x;
    if (idx >= HC * HC) return;
    int c = idx >> 7, k = idx & 127;
    __hip_bfloat16 v = __float2bfloat16(W2[k * HC + c]);
    W2T[idx] = (short)__hip_bfloat16_raw(v).x;
}

// ---- K1 (MFMA form, layer 2): h[n][c] = x[n][k] @ W2[k][c], bf16 in/out ----
// Per wave: one 16-node M-tile x 128 channels. A: lane holds x[m0+(l&15)]
// [kb*8..+7] per k-step; B: W2T[ct*16+(l&15)][kb*8..+7]; D: ch=ct*16+(l&15),
// node=m0+(l>>4)*4+r (verified C/D mapping).
__global__ __launch_bounds__(256) void k1_mfma(
    const __hip_bfloat16* __restrict__ xb,   // [N][128] bf16
    const short* __restrict__ W2T,           // [128][128] bf16, c-major
    __hip_bfloat16* __restrict__ hout)       // [N][128] bf16
{
    const int wave = threadIdx.x >> 6;
    const int lane = threadIdx.x & 63;
    const int tile = blockIdx.x * 4 + wave;
    if (tile >= N_NODES / 16) return;        // 3125 tiles, exact
    const int m0 = tile * 16;
    const int l15 = lane & 15;
    const int kb = lane >> 4;                // 0..3
    short8 a[4];
    const short* xrow = (const short*)(xb + (size_t)(m0 + l15) * HC);
#pragma unroll
    for (int kt = 0; kt < 4; kt++)
        a[kt] = *(const short8*)(xrow + kt * 32 + kb * 8);
#pragma unroll
    for (int ct = 0; ct < 8; ct++) {
        const short* wrow = W2T + (size_t)(ct * 16 + l15) * HC;
        f4v acc = {0.f, 0.f, 0.f, 0.f};
#pragma unroll
        for (int kt = 0; kt < 4; kt++) {
            short8 bfr = *(const short8*)(wrow + kt * 32 + kb * 8);
            acc = __builtin_amdgcn_mfma_f32_16x16x32_bf16(a[kt], bfr, acc, 0, 0, 0);
        }
#pragma unroll
        for (int r = 0; r < 4; r++) {
            int node = m0 + kb * 4 + r;
            int ch = ct * 16 + l15;
            hout[(size_t)node * HC + ch] = __float2bfloat16(acc[r]);
        }
    }
}

// ---- alpha from bf16 h: one wave per node, per-16-lane-head reduce ----
__global__ __launch_bounds__(256) void k_alpha(
    const unsigned* __restrict__ hb,   // [N][64] uints (2 bf16 per uint)
    const float* __restrict__ aS, const float* __restrict__ aD,
    float* __restrict__ asrc, float* __restrict__ adst)
{
    const int lane = threadIdx.x & 63;
    const int n = blockIdx.x * 4 + (threadIdx.x >> 6);
    if (n >= N_NODES) return;
    unsigned u = hb[(size_t)n * 64 + lane];
    float h0 = bflo(u), h1 = bfhi(u);
    float pa = h0 * aS[2 * lane] + h1 * aS[2 * lane + 1];
    float pb = h0 * aD[2 * lane] + h1 * aD[2 * lane + 1];
#pragma unroll
    for (int off = 8; off >= 1; off >>= 1) {
        pa += __shfl_xor(pa, off, 64);
        pb += __shfl_xor(pb, off, 64);
    }
    if ((lane & 15) == 0) {
        int head = lane >> 4;
        asrc[n * HEADS + head] = pa;
        adst[n * HEADS + head] = pb;
    }
}

// ---- CSR build: histogram(+rank) -> 3-phase scan -> atomic-free scatter ----
__global__ void kc_count(const int* __restrict__ ei1, int* __restrict__ cnt,
                         int* __restrict__ rank)
{
    int e = blockIdx.x * 256 + threadIdx.x;
    if (e >= E_EDGES) return;
    rank[e] = atomicAdd(&cnt[ei1[e]], 1);
}

__global__ __launch_bounds__(256) void kc_blocksum(const int* __restrict__ cnt,
                                                   int* __restrict__ bsum)
{
    __shared__ int sd[256];
    const int tid = threadIdx.x;
    int i = blockIdx.x * 256 + tid;
    int v = (i < N_NODES) ? cnt[i] : 0;
    sd[tid] = v;
    __syncthreads();
    for (int off = 128; off >= 1; off >>= 1) {
        if (tid < off) sd[tid] += sd[tid + off];
        __syncthreads();
    }
    if (tid == 0) bsum[blockIdx.x] = sd[0];
}

__global__ __launch_bounds__(256) void kc_scanbsum(const int* __restrict__ bsum,
                                                   int* __restrict__ bofs)
{
    __shared__ int sd[256];
    const int tid = threadIdx.x;
    int v = (tid < SCAN_NB) ? bsum[tid] : 0;
    sd[tid] = v;
    __syncthreads();
    for (int off = 1; off < 256; off <<= 1) {
        int u = (tid >= off) ? sd[tid - off] : 0;
        __syncthreads();
        sd[tid] += u;
        __syncthreads();
    }
    if (tid < SCAN_NB) bofs[tid] = sd[tid] - v;
}

__global__ __launch_bounds__(256) void kc_apply(const int* __restrict__ cnt,
                                                const int* __restrict__ bofs,
                                                int* __restrict__ rowptr)
{
    __shared__ int sd[256];
    const int tid = threadIdx.x;
    int i = blockIdx.x * 256 + tid;
    int v = (i < N_NODES) ? cnt[i] : 0;
    sd[tid] = v;
    __syncthreads();
    for (int off = 1; off < 256; off <<= 1) {
        int u = (tid >= off) ? sd[tid - off] : 0;
        __syncthreads();
        sd[tid] += u;
        __syncthreads();
    }
    int excl = sd[tid] - v + bofs[blockIdx.x];
    if (i < N_NODES) rowptr[i] = excl;
}

__global__ void kc_scatter(const int* __restrict__ ei0, const int* __restrict__ ei1,
                           const int* __restrict__ rowptr, const int* __restrict__ rank,
                           int* __restrict__ srcs)
{
    int e = blockIdx.x * 256 + threadIdx.x;
    if (e >= E_EDGES) return;
    srcs[rowptr[ei1[e]] + rank[e]] = ei0[e];
}

// ---- fused aggregation: fixed-reference segment softmax ----
template<int H, int C, bool DO_ELU, bool BF16H, bool OBF16>
__global__ __launch_bounds__(256) void k_aggr(
    const float* __restrict__ asrc, const float* __restrict__ adst,
    const void* __restrict__ hbuf, const int* __restrict__ rowptr,
    const int* __restrict__ deg, const int* __restrict__ srcs,
    const float* __restrict__ b, void* __restrict__ outp)
{
    constexpr int HCL = H * C;
    constexpr int TPE = HCL / 2;
    constexpr int NPB = 256 / TPE;
    constexpr bool UNI = (TPE == 64);
    const int t = threadIdx.x % TPE;
    const int n = blockIdx.x * NPB + threadIdx.x / TPE;
    if (n >= N_NODES) return;
    const int c0 = 2 * t;
    const int head = c0 / C;
    const float adstv = adst[n * H + head];
    const unsigned* hbu = (const unsigned*)hbuf;
    const float* hbf = (const float*)hbuf;
    const float m0 = lrelu(asrc[n * H + head] + adstv);
    float ssum = 1.f;
    float a0, a1;
    if (BF16H) {
        unsigned u = hbu[(size_t)n * TPE + t];
        a0 = bflo(u); a1 = bfhi(u);
    } else {
        float2 hv = *(const float2*)(hbf + (size_t)n * HCL + c0);
        a0 = hv.x; a1 = hv.y;
    }
    const int base = rowptr[n];
    const int dg = deg[n];
    int i = 0;

    if constexpr (UNI && BF16H) {
        for (; i + 8 <= dg; i += 8) {
            int s[8];
#pragma unroll
            for (int u = 0; u < 8; u++)
                s[u] = __builtin_amdgcn_readfirstlane(srcs[base + i + u]);
            float ex[8];
#pragma unroll
            for (int u = 0; u < 8; u++)
                ex[u] = __expf(lrelu(asrc[s[u] * H + head] + adstv) - m0);
            unsigned hu[8];
#pragma unroll
            for (int u = 0; u < 8; u++)
                hu[u] = hbu[(size_t)s[u] * TPE + t];
#pragma unroll
            for (int u = 0; u < 8; u++) {
                ssum += ex[u];
                a0 += ex[u] * bflo(hu[u]);
                a1 += ex[u] * bfhi(hu[u]);
            }
        }
    }

    for (; i + 4 <= dg; i += 4) {
        int s0 = srcs[base + i + 0];
        int s1 = srcs[base + i + 1];
        int s2 = srcs[base + i + 2];
        int s3 = srcs[base + i + 3];
        if (UNI) {
            s0 = __builtin_amdgcn_readfirstlane(s0);
            s1 = __builtin_amdgcn_readfirstlane(s1);
            s2 = __builtin_amdgcn_readfirstlane(s2);
            s3 = __builtin_amdgcn_readfirstlane(s3);
        }
        float ex[4];
        ex[0] = __expf(lrelu(asrc[s0 * H + head] + adstv) - m0);
        ex[1] = __expf(lrelu(asrc[s1 * H + head] + adstv) - m0);
        ex[2] = __expf(lrelu(asrc[s2 * H + head] + adstv) - m0);
        ex[3] = __expf(lrelu(asrc[s3 * H + head] + adstv) - m0);
        float hx[4], hy[4];
        if (BF16H) {
            unsigned u0 = hbu[(size_t)s0 * TPE + t];
            unsigned u1 = hbu[(size_t)s1 * TPE + t];
            unsigned u2 = hbu[(size_t)s2 * TPE + t];
            unsigned u3 = hbu[(size_t)s3 * TPE + t];
            hx[0] = bflo(u0); hy[0] = bfhi(u0);
            hx[1] = bflo(u1); hy[1] = bfhi(u1);
            hx[2] = bflo(u2); hy[2] = bfhi(u2);
            hx[3] = bflo(u3); hy[3] = bfhi(u3);
        } else {
            float2 h0 = *(const float2*)(hbf + (size_t)s0 * HCL + c0);
            float2 h1 = *(const float2*)(hbf + (size_t)s1 * HCL + c0);
            float2 h2 = *(const float2*)(hbf + (size_t)s2 * HCL + c0);
            float2 h3 = *(const float2*)(hbf + (size_t)s3 * HCL + c0);
            hx[0] = h0.x; hy[0] = h0.y;
            hx[1] = h1.x; hy[1] = h1.y;
            hx[2] = h2.x; hy[2] = h2.y;
            hx[3] = h3.x; hy[3] = h3.y;
        }
#pragma unroll
        for (int u = 0; u < 4; u++) {
            ssum += ex[u];
            a0 += ex[u] * hx[u];
            a1 += ex[u] * hy[u];
        }
    }
    for (; i < dg; i++) {
        int s = srcs[base + i];
        if (UNI) s = __builtin_amdgcn_readfirstlane(s);
        float ex = __expf(lrelu(asrc[s * H + head] + adstv) - m0);
        float hxv, hyv;
        if (BF16H) {
            unsigned u = hbu[(size_t)s * TPE + t];
            hxv = bflo(u); hyv = bfhi(u);
        } else {
            float2 hs = *(const float2*)(hbf + (size_t)s * HCL + c0);
            hxv = hs.x; hyv = hs.y;
        }
        ssum += ex;
        a0 += ex * hxv;
        a1 += ex * hyv;
    }
    float inv = 1.f / (ssum + 1e-16f);
    float v0 = a0 * inv + b[c0];
    float v1 = a1 * inv + b[c0 + 1];
    if (DO_ELU) {
        v0 = v0 > 0.f ? v0 : __expf(v0) - 1.f;
        v1 = v1 > 0.f ? v1 : __expf(v1) - 1.f;
    }
    if constexpr (OBF16) {
        __hip_bfloat16* ob = (__hip_bfloat16*)outp;
        ob[(size_t)n * HCL + c0]     = __float2bfloat16(v0);
        ob[(size_t)n * HCL + c0 + 1] = __float2bfloat16(v1);
    } else {
        *(float2*)((float*)outp + (size_t)n * HCL + c0) = make_float2(v0, v1);
    }
}

// ---- K5a: node-level precompute for MLP layer 1 (bf16 output) ----
__global__ __launch_bounds__(256) void k5a_precomp(
    const float* __restrict__ h3, const float* __restrict__ Wm1,
    __hip_bfloat16* __restrict__ Pb)
{
    __shared__ __align__(16) float w[64 * 32];
    __shared__ __align__(16) float hsh[16][33];
    const int tid = threadIdx.x;
    for (int i = tid; i < 64 * 32; i += 256) w[i] = Wm1[i];
    const int nb0 = blockIdx.x * 16;
    for (int idx = tid; idx < 16 * 32; idx += 256) {
        int node = idx / 32, k = idx % 32;
        int gn = nb0 + node;
        hsh[node][k] = (gn < N_NODES) ? h3[gn * 32 + k] : 0.f;
    }
    __syncthreads();
    const int c = tid % 64;
    const int part = c / 32;
    const int j = c % 32;
    for (int ln = tid / 64; ln < 16; ln += 4) {
        int gn = nb0 + ln;
        if (gn >= N_NODES) break;
        float sum = 0.f;
#pragma unroll
        for (int k = 0; k < 32; k++)
            sum += hsh[ln][k] * w[(part * 32 + k) * 32 + j];
        Pb[(size_t)gn * 64 + c] = __float2bfloat16(sum);
    }
}

// ---- K5b: per-edge MLP; scalar weights + packed f4v FMAs ----
__global__ __launch_bounds__(256, 4) void k5b_mlp(
                       const int* __restrict__ ei0, const int* __restrict__ ei1,
                       const __hip_bfloat16* __restrict__ Pb, const float* __restrict__ ea,
                       const float* __restrict__ Wm1, const float* __restrict__ bm1,
                       const float* __restrict__ Wm2, const float* __restrict__ bm2,
                       const float* __restrict__ Wm3, const float* __restrict__ bm3,
                       float* __restrict__ out)
{
    const int e = blockIdx.x * 256 + threadIdx.x;
    if (e >= E_EDGES) return;
    const int s = ei0[e], d = ei1[e];

    const f4v* bm1v = (const f4v*)bm1;
    f4v z1v[8];
#pragma unroll
    for (int q = 0; q < 8; q++) z1v[q] = bm1v[q];

    const f4v* eav = (const f4v*)(ea + (size_t)e * 8);
#pragma unroll
    for (int kq = 0; kq < 2; kq++) {
        f4v v = eav[kq];
#pragma unroll
        for (int r = 0; r < 4; r++) {
            float vr = (r == 0) ? v.x : (r == 1) ? v.y : (r == 2) ? v.z : v.w;
            const f4v* w4 = (const f4v*)(Wm1 + (64 + kq * 4 + r) * 32);
#pragma unroll
            for (int q = 0; q < 8; q++) z1v[q] += w4[q] * vr;
        }
    }
    const uint4* ps4 = (const uint4*)(Pb + (size_t)s * 64);
    const uint4* pd4 = (const uint4*)(Pb + (size_t)d * 64 + 32);
#pragma unroll
    for (int q = 0; q < 4; q++) {
        uint4 a = ps4[q];
        uint4 b = pd4[q];
        f4v pa0 = {bflo(a.x), bfhi(a.x), bflo(a.y), bfhi(a.y)};
        f4v pa1 = {bflo(a.z), bfhi(a.z), bflo(a.w), bfhi(a.w)};
        f4v pb0 = {bflo(b.x), bfhi(b.x), bflo(b.y), bfhi(b.y)};
        f4v pb1 = {bflo(b.z), bfhi(b.z), bflo(b.w), bfhi(b.w)};
        z1v[2 * q + 0] += pa0 + pb0;
        z1v[2 * q + 1] += pa1 + pb1;
    }
#pragma unroll
    for (int q = 0; q < 8; q++) z1v[q] = relu4(z1v[q]);

    const f4v* bm2v = (const f4v*)bm2;
    f4v acc2v[8];
#pragma unroll
    for (int q = 0; q < 8; q++) acc2v[q] = bm2v[q];
#pragma unroll
    for (int k = 0; k < 32; k++) {
        float zk = z1v[k >> 2][k & 3];
        const f4v* w4 = (const f4v*)(Wm2 + k * 32);
#pragma unroll
        for (int q = 0; q < 8; q++) acc2v[q] += w4[q] * zk;
    }
    float z3 = bm3[0];
#pragma unroll
    for (int q = 0; q < 8; q++) {
        const float* w3q = Wm3 + 4 * q;
        float c0 = acc2v[q].x, c1 = acc2v[q].y, c2 = acc2v[q].z, c3 = acc2v[q].w;
        z3 += (c0 > 0.f ? c0 : 0.f) * w3q[0];
        z3 += (c1 > 0.f ? c1 : 0.f) * w3q[1];
        z3 += (c2 > 0.f ? c2 : 0.f) * w3q[2];
        z3 += (c3 > 0.f ? c3 : 0.f) * w3q[3];
    }

    float r = (z3 > 20.f) ? z3 : log1pf(__expf(z3));
    __builtin_nontemporal_store(r, &out[e]);
}

extern "C" void kernel_launch(void* const* d_in, const int* in_sizes, int n_in,
                              void* d_out, int out_size, void* d_ws, size_t ws_size,
                              hipStream_t stream)
{
    const float* x   = (const float*)d_in[0];
    const int*   ei  = (const int*)d_in[1];
    const int*   ei0 = ei;
    const int*   ei1 = ei + E_EDGES;
    const float* ea  = (const float*)d_in[2];
    const float* W1  = (const float*)d_in[3];
    const float* aS1 = (const float*)d_in[4];
    const float* aD1 = (const float*)d_in[5];
    const float* b1  = (const float*)d_in[6];
    const float* W2  = (const float*)d_in[7];
    const float* aS2 = (const float*)d_in[8];
    const float* aD2 = (const float*)d_in[9];
    const float* b2  = (const float*)d_in[10];
    const float* W3  = (const float*)d_in[11];
    const float* aS3 = (const float*)d_in[12];
    const float* aD3 = (const float*)d_in[13];
    const float* b3  = (const float*)d_in[14];
    const float* Wm1 = (const float*)d_in[15];
    const float* bm1 = (const float*)d_in[16];
    const float* Wm2 = (const float*)d_in[17];
    const float* bm2 = (const float*)d_in[18];
    const float* Wm3 = (const float*)d_in[19];
    const float* bm3 = (const float*)d_in[20];

    float* ws = (float*)d_ws;
    float* bufA = ws;                                    // h buffer
    float* bufB = bufA + (size_t)N_NODES * HC;           // layer output
    float* asrc = bufB + (size_t)N_NODES * HC;           // [N,4]
    float* adst = asrc + (size_t)N_NODES * HEADS;        // [N,4]
    int* cnt    = (int*)(adst + (size_t)N_NODES * HEADS);// [N]
    int* rowptr = cnt + N_NODES;                         // [N]
    int* rank   = rowptr + N_NODES;                      // [E]
    int* srcs   = rank + E_EDGES;                        // [E]
    int* bsum   = srcs + E_EDGES;                        // [256]
    int* bofs   = bsum + 256;                            // [256]
    short* W2T  = (short*)(bofs + 256);                  // [128*128] bf16

    float* out = (float*)d_out;

    // ---------------- CSR build + W2 conversion ----------------
    hipMemsetAsync(cnt, 0, (size_t)N_NODES * sizeof(int), stream);
    kc_count<<<(E_EDGES + 255) / 256, 256, 0, stream>>>(ei1, cnt, rank);
    kw_conv<<<(HC * HC + 255) / 256, 256, 0, stream>>>(W2, W2T);
    kc_blocksum<<<SCAN_NB, 256, 0, stream>>>(cnt, bsum);
    kc_scanbsum<<<1, 256, 0, stream>>>(bsum, bofs);
    kc_apply<<<SCAN_NB, 256, 0, stream>>>(cnt, bofs, rowptr);
    kc_scatter<<<(E_EDGES + 255) / 256, 256, 0, stream>>>(ei0, ei1, rowptr, rank, srcs);

    // ---------------- Layer 1: x[N,16] -> bufB bf16 (ELU) ----------------
    k1_gemm_alpha<NFEAT, HC, HEADS, true, 4><<<(N_NODES + 7) / 8, 256, 0, stream>>>(
        x, W1, aS1, aD1, bufA, asrc, adst, N_NODES);
    k_aggr<HEADS, HID, true, true, true><<<(N_NODES + 3) / 4, 256, 0, stream>>>(
        asrc, adst, bufA, rowptr, cnt, srcs, b1, bufB);

    // ---------------- Layer 2: MFMA GEMM + alpha + aggr ----------------
    k1_mfma<<<(N_NODES / 16 + 3) / 4, 256, 0, stream>>>(
        (const __hip_bfloat16*)bufB, W2T, (__hip_bfloat16*)bufA);
    k_alpha<<<(N_NODES + 3) / 4, 256, 0, stream>>>(
        (const unsigned*)bufA, aS2, aD2, asrc, adst);
    k_aggr<HEADS, HID, true, true, false><<<(N_NODES + 3) / 4, 256, 0, stream>>>(
        asrc, adst, bufA, rowptr, cnt, srcs, b2, bufB);

    // ---------------- Layer 3: bufB(f32)[N,128] -> bufB[N,32] (H=1) ----------------
    k1_gemm_alpha<HC, HID, 1, false, 4><<<(N_NODES + 31) / 32, 256, 0, stream>>>(
        bufB, W3, aS3, aD3, bufA, asrc, adst, N_NODES);
    k_aggr<1, HID, false, false, false><<<(N_NODES + 15) / 16, 256, 0, stream>>>(
        asrc, adst, bufA, rowptr, cnt, srcs, b3, bufB);

    // ---------------- Edge MLP ----------------
    __hip_bfloat16* Pb = (__hip_bfloat16*)bufA;
    k5a_precomp<<<(N_NODES + 15) / 16, 256, 0, stream>>>(bufB, Wm1, Pb);
    k5b_mlp<<<(E_EDGES + 255) / 256, 256, 0, stream>>>(
        ei0, ei1, Pb, ea, Wm1, bm1, Wm2, bm2, Wm3, bm3, out);
}

// Round 20
// 277.119 us; speedup vs baseline: 1.2060x; 1.0513x over previous
//
#include <hip/hip_runtime.h>
#include <hip/hip_bf16.h>
#include <math.h>

#define N_NODES 50000
#define E_EDGES 800000
#define NFEAT 16
#define EFEAT 8
#define HID 32
#define HEADS 4
#define HC 128
#define SCAN_NB ((N_NODES + 255) / 256)   // 196

typedef float f4v __attribute__((ext_vector_type(4)));
typedef short short8 __attribute__((ext_vector_type(8)));

__device__ __forceinline__ float lrelu(float v) { return v > 0.f ? v : 0.2f * v; }
__device__ __forceinline__ float bflo(unsigned u) { return __uint_as_float(u << 16); }
__device__ __forceinline__ float bfhi(unsigned u) { return __uint_as_float(u & 0xffff0000u); }
__device__ __forceinline__ f4v relu4(f4v v) {
    f4v r;
    r.x = v.x > 0.f ? v.x : 0.f;
    r.y = v.y > 0.f ? v.y : 0.f;
    r.z = v.z > 0.f ? v.z : 0.f;
    r.w = v.w > 0.f ? v.w : 0.f;
    return r;
}

// ---- K1 (VALU form, layers 1 & 3): h = x @ W ; alpha via shfl-reduce ----
template<int FIN, int HOUT, int H, bool BF16OUT, int NPT>
__global__ void k1_gemm_alpha(const float* __restrict__ x, const float* __restrict__ W,
                              const float* __restrict__ aS, const float* __restrict__ aD,
                              void* __restrict__ hout, float* __restrict__ asrc,
                              float* __restrict__ adst, int n_nodes)
{
    constexpr int GROUPS = 256 / HOUT;
    constexpr int NPB = GROUPS * NPT;
    constexpr bool SCALARX = (HOUT >= 64);
    __shared__ float xs[SCALARX ? 1 : NPB * (FIN + 1)];
    const int tid = threadIdx.x;
    const int nb0 = blockIdx.x * NPB;
    const int c = tid % HOUT;
    const int g = tid / HOUT;

    if constexpr (!SCALARX) {
        for (int idx = tid; idx < NPB * FIN; idx += 256) {
            int node = idx / FIN, k = idx % FIN;
            int gn = nb0 + node;
            xs[node * (FIN + 1) + k] = (gn < n_nodes) ? x[(size_t)gn * FIN + k] : 0.f;
        }
        __syncthreads();
    }

    const int head = c / HID;
    const int cc = c % HID;
    const float aSv = aS[head * HID + cc];
    const float aDv = aD[head * HID + cc];
    float acc[NPT];
#pragma unroll
    for (int i = 0; i < NPT; i++) acc[i] = 0.f;

    if constexpr (SCALARX) {
        const float* xr[NPT];
#pragma unroll
        for (int i = 0; i < NPT; i++) {
            int n = nb0 + g * NPT + i;
            unsigned nu = (unsigned)__builtin_amdgcn_readfirstlane(n < n_nodes ? n : 0);
            xr[i] = x + (size_t)nu * FIN;
        }
#pragma unroll 8
        for (int k = 0; k < FIN; k++) {
            float w = W[k * HOUT + c];
#pragma unroll
            for (int i = 0; i < NPT; i++) acc[i] += w * xr[i][k];
        }
    } else {
        for (int k = 0; k < FIN; k++) {
            float w = W[k * HOUT + c];
#pragma unroll
            for (int i = 0; i < NPT; i++)
                acc[i] += w * xs[(g * NPT + i) * (FIN + 1) + k];
        }
    }

#pragma unroll
    for (int i = 0; i < NPT; i++) {
        int n = nb0 + g * NPT + i;
        bool ok = (n < n_nodes);
        float h = acc[i];
        if (ok) {
            if (BF16OUT)
                ((__hip_bfloat16*)hout)[(size_t)n * HOUT + c] = __float2bfloat16(h);
            else
                ((float*)hout)[(size_t)n * HOUT + c] = h;
        }
        float pa = h * aSv, pb = h * aDv;
#pragma unroll
        for (int off = 16; off >= 1; off >>= 1) {
            pa += __shfl_xor(pa, off, 32);
            pb += __shfl_xor(pb, off, 32);
        }
        if (ok && cc == 0) { asrc[n * H + head] = pa; adst[n * H + head] = pb; }
    }
}

// ---- W2 -> bf16 transposed [c][k] for MFMA B-fragments ----
__global__ __launch_bounds__(256) void kw_conv(const float* __restrict__ W2,
                                               short* __restrict__ W2T)
{
    int idx = blockIdx.x * 256 + threadIdx.x;
    if (idx >= HC * HC) return;
    int c = idx >> 7, k = idx & 127;
    __hip_bfloat16 v = __float2bfloat16(W2[k * HC + c]);
    W2T[idx] = (short)__hip_bfloat16_raw(v).x;
}

// ---- K1 (MFMA form, layer 2) ----
__global__ __launch_bounds__(256) void k1_mfma(
    const __hip_bfloat16* __restrict__ xb,   // [N][128] bf16
    const short* __restrict__ W2T,           // [128][128] bf16, c-major
    __hip_bfloat16* __restrict__ hout)       // [N][128] bf16
{
    const int wave = threadIdx.x >> 6;
    const int lane = threadIdx.x & 63;
    const int tile = blockIdx.x * 4 + wave;
    if (tile >= N_NODES / 16) return;        // 3125 tiles, exact
    const int m0 = tile * 16;
    const int l15 = lane & 15;
    const int kb = lane >> 4;                // 0..3
    short8 a[4];
    const short* xrow = (const short*)(xb + (size_t)(m0 + l15) * HC);
#pragma unroll
    for (int kt = 0; kt < 4; kt++)
        a[kt] = *(const short8*)(xrow + kt * 32 + kb * 8);
#pragma unroll
    for (int ct = 0; ct < 8; ct++) {
        const short* wrow = W2T + (size_t)(ct * 16 + l15) * HC;
        f4v acc = {0.f, 0.f, 0.f, 0.f};
#pragma unroll
        for (int kt = 0; kt < 4; kt++) {
            short8 bfr = *(const short8*)(wrow + kt * 32 + kb * 8);
            acc = __builtin_amdgcn_mfma_f32_16x16x32_bf16(a[kt], bfr, acc, 0, 0, 0);
        }
#pragma unroll
        for (int r = 0; r < 4; r++) {
            int node = m0 + kb * 4 + r;
            int ch = ct * 16 + l15;
            hout[(size_t)node * HC + ch] = __float2bfloat16(acc[r]);
        }
    }
}

// ---- alpha from bf16 h: one wave per node, per-16-lane-head reduce ----
__global__ __launch_bounds__(256) void k_alpha(
    const unsigned* __restrict__ hb,   // [N][64] uints (2 bf16 per uint)
    const float* __restrict__ aS, const float* __restrict__ aD,
    float* __restrict__ asrc, float* __restrict__ adst)
{
    const int lane = threadIdx.x & 63;
    const int n = blockIdx.x * 4 + (threadIdx.x >> 6);
    if (n >= N_NODES) return;
    unsigned u = hb[(size_t)n * 64 + lane];
    float h0 = bflo(u), h1 = bfhi(u);
    float pa = h0 * aS[2 * lane] + h1 * aS[2 * lane + 1];
    float pb = h0 * aD[2 * lane] + h1 * aD[2 * lane + 1];
#pragma unroll
    for (int off = 8; off >= 1; off >>= 1) {
        pa += __shfl_xor(pa, off, 64);
        pb += __shfl_xor(pb, off, 64);
    }
    if ((lane & 15) == 0) {
        int head = lane >> 4;
        asrc[n * HEADS + head] = pa;
        adst[n * HEADS + head] = pb;
    }
}

// ---- CSR build: histogram(+rank) -> 3-phase scan -> atomic-free scatter ----
__global__ void kc_count(const int* __restrict__ ei1, int* __restrict__ cnt,
                         int* __restrict__ rank)
{
    int e = blockIdx.x * 256 + threadIdx.x;
    if (e >= E_EDGES) return;
    rank[e] = atomicAdd(&cnt[ei1[e]], 1);
}

__global__ __launch_bounds__(256) void kc_blocksum(const int* __restrict__ cnt,
                                                   int* __restrict__ bsum)
{
    __shared__ int sd[256];
    const int tid = threadIdx.x;
    int i = blockIdx.x * 256 + tid;
    int v = (i < N_NODES) ? cnt[i] : 0;
    sd[tid] = v;
    __syncthreads();
    for (int off = 128; off >= 1; off >>= 1) {
        if (tid < off) sd[tid] += sd[tid + off];
        __syncthreads();
    }
    if (tid == 0) bsum[blockIdx.x] = sd[0];
}

__global__ __launch_bounds__(256) void kc_scanbsum(const int* __restrict__ bsum,
                                                   int* __restrict__ bofs)
{
    __shared__ int sd[256];
    const int tid = threadIdx.x;
    int v = (tid < SCAN_NB) ? bsum[tid] : 0;
    sd[tid] = v;
    __syncthreads();
    for (int off = 1; off < 256; off <<= 1) {
        int u = (tid >= off) ? sd[tid - off] : 0;
        __syncthreads();
        sd[tid] += u;
        __syncthreads();
    }
    if (tid < SCAN_NB) bofs[tid] = sd[tid] - v;
}

__global__ __launch_bounds__(256) void kc_apply(const int* __restrict__ cnt,
                                                const int* __restrict__ bofs,
                                                int* __restrict__ rowptr)
{
    __shared__ int sd[256];
    const int tid = threadIdx.x;
    int i = blockIdx.x * 256 + tid;
    int v = (i < N_NODES) ? cnt[i] : 0;
    sd[tid] = v;
    __syncthreads();
    for (int off = 1; off < 256; off <<= 1) {
        int u = (tid >= off) ? sd[tid - off] : 0;
        __syncthreads();
        sd[tid] += u;
        __syncthreads();
    }
    int excl = sd[tid] - v + bofs[blockIdx.x];
    if (i < N_NODES) rowptr[i] = excl;
}

__global__ void kc_scatter(const int* __restrict__ ei0, const int* __restrict__ ei1,
                           const int* __restrict__ rowptr, const int* __restrict__ rank,
                           int* __restrict__ srcs)
{
    int e = blockIdx.x * 256 + threadIdx.x;
    if (e >= E_EDGES) return;
    srcs[rowptr[ei1[e]] + rank[e]] = ei0[e];
}

// ---- fused aggregation: fixed-reference segment softmax ----
// FUSE_P (layer 3 only, TPE=16): instead of writing h3, compute
// P[n][0:64] = h3 . [W1a | W1b] in-register (16-lane group holds the full
// 32-ch row; 16 shfl broadcasts, k ascending) and write bf16 P directly.
template<int H, int C, bool DO_ELU, bool BF16H, bool OBF16, bool FUSE_P>
__global__ __launch_bounds__(256) void k_aggr(
    const float* __restrict__ asrc, const float* __restrict__ adst,
    const void* __restrict__ hbuf, const int* __restrict__ rowptr,
    const int* __restrict__ deg, const int* __restrict__ srcs,
    const float* __restrict__ b, void* __restrict__ outp,
    const float* __restrict__ Wm1)
{
    constexpr int HCL = H * C;
    constexpr int TPE = HCL / 2;
    constexpr int NPB = 256 / TPE;
    constexpr bool UNI = (TPE == 64);
    const int t = threadIdx.x % TPE;
    const int n = blockIdx.x * NPB + threadIdx.x / TPE;
    if (n >= N_NODES) return;
    const int c0 = 2 * t;
    const int head = c0 / C;
    const float adstv = adst[n * H + head];
    const unsigned* hbu = (const unsigned*)hbuf;
    const float* hbf = (const float*)hbuf;
    const float m0 = lrelu(asrc[n * H + head] + adstv);
    float ssum = 1.f;
    float a0, a1;
    if (BF16H) {
        unsigned u = hbu[(size_t)n * TPE + t];
        a0 = bflo(u); a1 = bfhi(u);
    } else {
        float2 hv = *(const float2*)(hbf + (size_t)n * HCL + c0);
        a0 = hv.x; a1 = hv.y;
    }
    const int base = rowptr[n];
    const int dg = deg[n];
    int i = 0;

    if constexpr (UNI && BF16H) {
        for (; i + 8 <= dg; i += 8) {
            int s[8];
#pragma unroll
            for (int u = 0; u < 8; u++)
                s[u] = __builtin_amdgcn_readfirstlane(srcs[base + i + u]);
            float ex[8];
#pragma unroll
            for (int u = 0; u < 8; u++)
                ex[u] = __expf(lrelu(asrc[s[u] * H + head] + adstv) - m0);
            unsigned hu[8];
#pragma unroll
            for (int u = 0; u < 8; u++)
                hu[u] = hbu[(size_t)s[u] * TPE + t];
#pragma unroll
            for (int u = 0; u < 8; u++) {
                ssum += ex[u];
                a0 += ex[u] * bflo(hu[u]);
                a1 += ex[u] * bfhi(hu[u]);
            }
        }
    }

    for (; i + 4 <= dg; i += 4) {
        int s0 = srcs[base + i + 0];
        int s1 = srcs[base + i + 1];
        int s2 = srcs[base + i + 2];
        int s3 = srcs[base + i + 3];
        if (UNI) {
            s0 = __builtin_amdgcn_readfirstlane(s0);
            s1 = __builtin_amdgcn_readfirstlane(s1);
            s2 = __builtin_amdgcn_readfirstlane(s2);
            s3 = __builtin_amdgcn_readfirstlane(s3);
        }
        float ex[4];
        ex[0] = __expf(lrelu(asrc[s0 * H + head] + adstv) - m0);
        ex[1] = __expf(lrelu(asrc[s1 * H + head] + adstv) - m0);
        ex[2] = __expf(lrelu(asrc[s2 * H + head] + adstv) - m0);
        ex[3] = __expf(lrelu(asrc[s3 * H + head] + adstv) - m0);
        float hx[4], hy[4];
        if (BF16H) {
            unsigned u0 = hbu[(size_t)s0 * TPE + t];
            unsigned u1 = hbu[(size_t)s1 * TPE + t];
            unsigned u2 = hbu[(size_t)s2 * TPE + t];
            unsigned u3 = hbu[(size_t)s3 * TPE + t];
            hx[0] = bflo(u0); hy[0] = bfhi(u0);
            hx[1] = bflo(u1); hy[1] = bfhi(u1);
            hx[2] = bflo(u2); hy[2] = bfhi(u2);
            hx[3] = bflo(u3); hy[3] = bfhi(u3);
        } else {
            float2 h0 = *(const float2*)(hbf + (size_t)s0 * HCL + c0);
            float2 h1 = *(const float2*)(hbf + (size_t)s1 * HCL + c0);
            float2 h2 = *(const float2*)(hbf + (size_t)s2 * HCL + c0);
            float2 h3 = *(const float2*)(hbf + (size_t)s3 * HCL + c0);
            hx[0] = h0.x; hy[0] = h0.y;
            hx[1] = h1.x; hy[1] = h1.y;
            hx[2] = h2.x; hy[2] = h2.y;
            hx[3] = h3.x; hy[3] = h3.y;
        }
#pragma unroll
        for (int u = 0; u < 4; u++) {
            ssum += ex[u];
            a0 += ex[u] * hx[u];
            a1 += ex[u] * hy[u];
        }
    }
    for (; i < dg; i++) {
        int s = srcs[base + i];
        if (UNI) s = __builtin_amdgcn_readfirstlane(s);
        float ex = __expf(lrelu(asrc[s * H + head] + adstv) - m0);
        float hxv, hyv;
        if (BF16H) {
            unsigned u = hbu[(size_t)s * TPE + t];
            hxv = bflo(u); hyv = bfhi(u);
        } else {
            float2 hs = *(const float2*)(hbf + (size_t)s * HCL + c0);
            hxv = hs.x; hyv = hs.y;
        }
        ssum += ex;
        a0 += ex * hxv;
        a1 += ex * hyv;
    }
    float inv = 1.f / (ssum + 1e-16f);
    float v0 = a0 * inv + b[c0];
    float v1 = a1 * inv + b[c0 + 1];
    if (DO_ELU) {
        v0 = v0 > 0.f ? v0 : __expf(v0) - 1.f;
        v1 = v1 > 0.f ? v1 : __expf(v1) - 1.f;
    }
    if constexpr (FUSE_P) {
        // 16-lane group holds full 32-ch h3 row (2/lane). Compute
        // P[n][4t..4t+3] = sum_k h3[k] * Wm1[part*32+k][col..col+3].
        const int lane = threadIdx.x & 63;
        const int sb = lane & ~15;
        const int part = (t >= 8) ? 1 : 0;
        const int col = (4 * t) & 31;
        f4v pacc = {0.f, 0.f, 0.f, 0.f};
#pragma unroll
        for (int j = 0; j < 16; j++) {
            float h0 = __shfl(v0, sb + j, 64);
            float h1 = __shfl(v1, sb + j, 64);
            const f4v w0 = *(const f4v*)(Wm1 + (size_t)(part * 32 + 2 * j) * 32 + col);
            const f4v w1 = *(const f4v*)(Wm1 + (size_t)(part * 32 + 2 * j + 1) * 32 + col);
            pacc += w0 * h0;
            pacc += w1 * h1;
        }
        __hip_bfloat16* pb = (__hip_bfloat16*)outp + (size_t)n * 64 + 4 * t;
        unsigned p01 = ((unsigned)__hip_bfloat16_raw(__float2bfloat16(pacc.x)).x) |
                       (((unsigned)__hip_bfloat16_raw(__float2bfloat16(pacc.y)).x) << 16);
        unsigned p23 = ((unsigned)__hip_bfloat16_raw(__float2bfloat16(pacc.z)).x) |
                       (((unsigned)__hip_bfloat16_raw(__float2bfloat16(pacc.w)).x) << 16);
        uint2 pk = {p01, p23};
        *(uint2*)pb = pk;
    } else if constexpr (OBF16) {
        __hip_bfloat16* ob = (__hip_bfloat16*)outp;
        ob[(size_t)n * HCL + c0]     = __float2bfloat16(v0);
        ob[(size_t)n * HCL + c0 + 1] = __float2bfloat16(v1);
    } else {
        *(float2*)((float*)outp + (size_t)n * HCL + c0) = make_float2(v0, v1);
    }
}

// ---- K5b: per-edge MLP; scalar weights + packed f4v FMAs ----
__global__ __launch_bounds__(256, 4) void k5b_mlp(
                       const int* __restrict__ ei0, const int* __restrict__ ei1,
                       const __hip_bfloat16* __restrict__ Pb, const float* __restrict__ ea,
                       const float* __restrict__ Wm1, const float* __restrict__ bm1,
                       const float* __restrict__ Wm2, const float* __restrict__ bm2,
                       const float* __restrict__ Wm3, const float* __restrict__ bm3,
                       float* __restrict__ out)
{
    const int e = blockIdx.x * 256 + threadIdx.x;
    if (e >= E_EDGES) return;
    const int s = ei0[e], d = ei1[e];

    const f4v* bm1v = (const f4v*)bm1;
    f4v z1v[8];
#pragma unroll
    for (int q = 0; q < 8; q++) z1v[q] = bm1v[q];

    const f4v* eav = (const f4v*)(ea + (size_t)e * 8);
#pragma unroll
    for (int kq = 0; kq < 2; kq++) {
        f4v v = eav[kq];
#pragma unroll
        for (int r = 0; r < 4; r++) {
            float vr = (r == 0) ? v.x : (r == 1) ? v.y : (r == 2) ? v.z : v.w;
            const f4v* w4 = (const f4v*)(Wm1 + (64 + kq * 4 + r) * 32);
#pragma unroll
            for (int q = 0; q < 8; q++) z1v[q] += w4[q] * vr;
        }
    }
    const uint4* ps4 = (const uint4*)(Pb + (size_t)s * 64);
    const uint4* pd4 = (const uint4*)(Pb + (size_t)d * 64 + 32);
#pragma unroll
    for (int q = 0; q < 4; q++) {
        uint4 a = ps4[q];
        uint4 b = pd4[q];
        f4v pa0 = {bflo(a.x), bfhi(a.x), bflo(a.y), bfhi(a.y)};
        f4v pa1 = {bflo(a.z), bfhi(a.z), bflo(a.w), bfhi(a.w)};
        f4v pb0 = {bflo(b.x), bfhi(b.x), bflo(b.y), bfhi(b.y)};
        f4v pb1 = {bflo(b.z), bfhi(b.z), bflo(b.w), bfhi(b.w)};
        z1v[2 * q + 0] += pa0 + pb0;
        z1v[2 * q + 1] += pa1 + pb1;
    }
#pragma unroll
    for (int q = 0; q < 8; q++) z1v[q] = relu4(z1v[q]);

    const f4v* bm2v = (const f4v*)bm2;
    f4v acc2v[8];
#pragma unroll
    for (int q = 0; q < 8; q++) acc2v[q] = bm2v[q];
#pragma unroll
    for (int k = 0; k < 32; k++) {
        float zk = z1v[k >> 2][k & 3];
        const f4v* w4 = (const f4v*)(Wm2 + k * 32);
#pragma unroll
        for (int q = 0; q < 8; q++) acc2v[q] += w4[q] * zk;
    }
    float z3 = bm3[0];
#pragma unroll
    for (int q = 0; q < 8; q++) {
        const float* w3q = Wm3 + 4 * q;
        float c0 = acc2v[q].x, c1 = acc2v[q].y, c2 = acc2v[q].z, c3 = acc2v[q].w;
        z3 += (c0 > 0.f ? c0 : 0.f) * w3q[0];
        z3 += (c1 > 0.f ? c1 : 0.f) * w3q[1];
        z3 += (c2 > 0.f ? c2 : 0.f) * w3q[2];
        z3 += (c3 > 0.f ? c3 : 0.f) * w3q[3];
    }

    float r = (z3 > 20.f) ? z3 : log1pf(__expf(z3));
    __builtin_nontemporal_store(r, &out[e]);
}

extern "C" void kernel_launch(void* const* d_in, const int* in_sizes, int n_in,
                              void* d_out, int out_size, void* d_ws, size_t ws_size,
                              hipStream_t stream)
{
    const float* x   = (const float*)d_in[0];
    const int*   ei  = (const int*)d_in[1];
    const int*   ei0 = ei;
    const int*   ei1 = ei + E_EDGES;
    const float* ea  = (const float*)d_in[2];
    const float* W1  = (const float*)d_in[3];
    const float* aS1 = (const float*)d_in[4];
    const float* aD1 = (const float*)d_in[5];
    const float* b1  = (const float*)d_in[6];
    const float* W2  = (const float*)d_in[7];
    const float* aS2 = (const float*)d_in[8];
    const float* aD2 = (const float*)d_in[9];
    const float* b2  = (const float*)d_in[10];
    const float* W3  = (const float*)d_in[11];
    const float* aS3 = (const float*)d_in[12];
    const float* aD3 = (const float*)d_in[13];
    const float* b3  = (const float*)d_in[14];
    const float* Wm1 = (const float*)d_in[15];
    const float* bm1 = (const float*)d_in[16];
    const float* Wm2 = (const float*)d_in[17];
    const float* bm2 = (const float*)d_in[18];
    const float* Wm3 = (const float*)d_in[19];
    const float* bm3 = (const float*)d_in[20];

    float* ws = (float*)d_ws;
    float* bufA = ws;                                    // h buffer
    float* bufB = bufA + (size_t)N_NODES * HC;           // layer output / Pb
    float* asrc = bufB + (size_t)N_NODES * HC;           // [N,4]
    float* adst = asrc + (size_t)N_NODES * HEADS;        // [N,4]
    int* cnt    = (int*)(adst + (size_t)N_NODES * HEADS);// [N]
    int* rowptr = cnt + N_NODES;                         // [N]
    int* rank   = rowptr + N_NODES;                      // [E]
    int* srcs   = rank + E_EDGES;                        // [E]
    int* bsum   = srcs + E_EDGES;                        // [256]
    int* bofs   = bsum + 256;                            // [256]
    short* W2T  = (short*)(bofs + 256);                  // [128*128] bf16

    float* out = (float*)d_out;

    // ---------------- CSR build + W2 conversion ----------------
    hipMemsetAsync(cnt, 0, (size_t)N_NODES * sizeof(int), stream);
    kc_count<<<(E_EDGES + 255) / 256, 256, 0, stream>>>(ei1, cnt, rank);
    kw_conv<<<(HC * HC + 255) / 256, 256, 0, stream>>>(W2, W2T);
    kc_blocksum<<<SCAN_NB, 256, 0, stream>>>(cnt, bsum);
    kc_scanbsum<<<1, 256, 0, stream>>>(bsum, bofs);
    kc_apply<<<SCAN_NB, 256, 0, stream>>>(cnt, bofs, rowptr);
    kc_scatter<<<(E_EDGES + 255) / 256, 256, 0, stream>>>(ei0, ei1, rowptr, rank, srcs);

    // ---------------- Layer 1: x[N,16] -> bufB bf16 (ELU) ----------------
    k1_gemm_alpha<NFEAT, HC, HEADS, true, 4><<<(N_NODES + 7) / 8, 256, 0, stream>>>(
        x, W1, aS1, aD1, bufA, asrc, adst, N_NODES);
    k_aggr<HEADS, HID, true, true, true, false><<<(N_NODES + 3) / 4, 256, 0, stream>>>(
        asrc, adst, bufA, rowptr, cnt, srcs, b1, bufB, Wm1);

    // ---------------- Layer 2: MFMA GEMM + alpha + aggr ----------------
    k1_mfma<<<(N_NODES / 16 + 3) / 4, 256, 0, stream>>>(
        (const __hip_bfloat16*)bufB, W2T, (__hip_bfloat16*)bufA);
    k_alpha<<<(N_NODES + 3) / 4, 256, 0, stream>>>(
        (const unsigned*)bufA, aS2, aD2, asrc, adst);
    k_aggr<HEADS, HID, true, true, false, false><<<(N_NODES + 3) / 4, 256, 0, stream>>>(
        asrc, adst, bufA, rowptr, cnt, srcs, b2, bufB, Wm1);

    // ---------------- Layer 3: k1 + aggr with fused P computation ----------------
    k1_gemm_alpha<HC, HID, 1, false, 4><<<(N_NODES + 31) / 32, 256, 0, stream>>>(
        bufB, W3, aS3, aD3, bufA, asrc, adst, N_NODES);
    // reads h (bufA f32), writes Pb (bf16) into bufB directly — k5a eliminated
    k_aggr<1, HID, false, false, false, true><<<(N_NODES + 15) / 16, 256, 0, stream>>>(
        asrc, adst, bufA, rowptr, cnt, srcs, b3, bufB, Wm1);

    // ---------------- Edge MLP ----------------
    __hip_bfloat16* Pb = (__hip_bfloat16*)bufB;
    k5b_mlp<<<(E_EDGES + 255) / 256, 256, 0, stream>>>(
        ei0, ei1, Pb, ea, Wm1, bm1, Wm2, bm2, Wm3, bm3, out);
}